// Round 11
// baseline (917.958 us; speedup 1.0000x reference)
//
#include <hip/hip_runtime.h>

typedef short short8 __attribute__((ext_vector_type(8)));
typedef float floatx4 __attribute__((ext_vector_type(4)));

#define GPB 8        // graphs per block -> 512 blocks = exactly 2 resident per CU
#define ORD_CAP 1184 // preloaded order[] entries (span ~977 +- 31; ~6.6 sigma headroom)

__device__ __forceinline__ unsigned short f2bf(float x) {
  union { float f; unsigned int u; } c; c.f = x;
  return (unsigned short)((c.u + 0x7FFFu + ((c.u >> 16) & 1u)) >> 16);
}

__device__ __forceinline__ unsigned cvtpk(float lo, float hi) {
  unsigned r;
  asm("v_cvt_pk_bf16_f32 %0, %1, %2" : "=v"(r) : "v"(lo), "v"(hi));
  return r;
}

__device__ __forceinline__ void gld16(const void* g, void* l) {
  __builtin_amdgcn_global_load_lds((const __attribute__((address_space(1))) void*)g,
                                   (__attribute__((address_space(3))) void*)l, 16, 0, 0);
}

__global__ void k_hist(const int* __restrict__ gid, int L, int* __restrict__ counts) {
  int i = blockIdx.x * blockDim.x + threadIdx.x;
  if (i < L) atomicAdd(&counts[gid[i]], 1);
}

__global__ void k_scan(const int* __restrict__ counts, int* __restrict__ offsets,
                       int* __restrict__ cursor, int G) {
  __shared__ int sc[1024];
  int t = threadIdx.x;
  int items = (G + 1023) >> 10;
  int base = t * items;
  int s = 0;
  for (int i = 0; i < items; ++i) { int idx = base + i; if (idx < G) s += counts[idx]; }
  sc[t] = s;
  __syncthreads();
  for (int off = 1; off < 1024; off <<= 1) {
    int v = (t >= off) ? sc[t - off] : 0;
    __syncthreads();
    if (t >= off) sc[t] += v;
    __syncthreads();
  }
  int run = (t == 0) ? 0 : sc[t - 1];
  for (int i = 0; i < items; ++i) {
    int idx = base + i;
    if (idx < G) { offsets[idx] = run; cursor[idx] = run; run += counts[idx]; }
  }
  if (t == 1023) offsets[G] = sc[1023];
}

__global__ void k_scatter(const int* __restrict__ gid, int L, int* __restrict__ cursor,
                          int* __restrict__ order) {
  int i = blockIdx.x * blockDim.x + threadIdx.x;
  if (i < L) {
    int g = gid[i];
    int pos = atomicAdd(&cursor[g], 1);
    order[pos] = i;
  }
}

// W2 [512][256] bf16, 4-wave layout: row j2 = 128*w + 64*half + c -> d = 64*w + c
// (half 0 = key, 1 = value). Wave w's 128 rows cover its 64-col d-range for BOTH proj.
__global__ void k_prepw(const float* __restrict__ keyW, const float* __restrict__ valW,
                        unsigned short* __restrict__ W2) {
  int j2 = blockIdx.x;
  int k = threadIdx.x;
  int wv = j2 >> 7, half = (j2 >> 6) & 1, c = j2 & 63;
  int d = (wv << 6) + c;
  const float* src = half ? valW : keyW;
  W2[j2 * 256 + k] = f2bf(src[d * 256 + k]);
}

__launch_bounds__(256, 2)
__global__ void k_fused(const float* __restrict__ fnode,
                        const unsigned short* __restrict__ W2,
                        const float* __restrict__ key_b, const float* __restrict__ value_b,
                        const float* __restrict__ gamma, const float* __restrict__ beta,
                        const int* __restrict__ order, const int* __restrict__ offsets,
                        float* __restrict__ out, int L, int Gtot) {
  // A dbuf: 2 x (32 rows x 1KB f32), filled by global_load_lds.
  // LDS 16B-slot s of row r holds global slot s ^ (r&7) (source-side XOR swizzle).
  __shared__ __align__(16) float As[2][32 * 256];
  __shared__ int ord_s[ORD_CAP];
  __shared__ float fg[GPB][256];
  __shared__ int eb[GPB + 1];
  __shared__ float redS[4], redS2[4];

  const int t = threadIdx.x;
  const int lane = t & 63;
  const int w = t >> 6;        // wave 0..3 -> d range [64w, 64w+64)
  const int lcol = lane & 15;
  const int lrow = lane >> 4;
  const int g0 = blockIdx.x * GPB;

  if (t <= GPB) eb[t] = offsets[min(g0 + t, Gtot)];
  __syncthreads();
  const int rbase = eb[0];
  const int span = eb[GPB] - rbase;
  const int nc = max(1, (span + 31) >> 5);

  for (int i = t; i < ORD_CAP; i += 256) ord_s[i] = order[min(rbase + i, L - 1)];

  float kb[4], vb[4];
#pragma unroll
  for (int nj = 0; nj < 4; ++nj) {
    int d = (w << 6) + (nj << 4) + lcol;
    kb[nj] = key_b[d];
    vb[nj] = value_b[d];
  }
  // B base: row j2 = 128w + nj*16 + lcol (nj 0-3 key, 4-7 val of same d)
  const unsigned short* Wb = W2 + ((size_t)((w << 7) + lcol)) * 256 + lrow * 8;
  short8 bp[8][4];  // kk 0..3 register-resident (128 VGPR); kk 4..7 streamed from L2
#pragma unroll
  for (int nj = 0; nj < 8; ++nj)
#pragma unroll
    for (int kk = 0; kk < 4; ++kk)
      bp[nj][kk] = *reinterpret_cast<const short8*>(Wb + (size_t)nj * 4096 + (kk << 5));

  __syncthreads();  // ord_s ready

  // stage chunk c into buffer buf: wave w gathers rows [8w, 8w+8), 1KB row per gld16x64
  auto stage = [&](int c, int buf) {
    const int m0 = c << 5;
#pragma unroll
    for (int it = 0; it < 8; ++it) {
      int gi = m0 + (w << 3) + it;
      if (gi > span - 1) gi = span - 1;
      if (gi < 0) gi = 0;
      const int idx = (gi < ORD_CAP) ? ord_s[gi] : order[rbase + gi];
      const char* gsrc =
          (const char*)fnode + ((size_t)idx << 10) + ((lane << 4) ^ (it << 4));
      gld16(gsrc, (char*)&As[buf][0] + (((w << 3) + it) << 10));
    }
  };

  stage(0, 0);
  if (nc > 1) {
    stage(1, 1);
    asm volatile("s_waitcnt vmcnt(8)" ::: "memory");  // chunk 0's 8 gld retired (FIFO)
  } else {
    asm volatile("s_waitcnt vmcnt(0)" ::: "memory");
  }
  __builtin_amdgcn_s_barrier();

  int curg = 0, flushed = 0;
  int ecur = eb[1] - rbase;
  float den[4] = {0.f, 0.f, 0.f, 0.f};
  float num[4] = {0.f, 0.f, 0.f, 0.f};

  for (int c = 0; c < nc; ++c) {
    // ---- MFMA on chunk c (A from LDS f32->bf16 at frag load; B regs + kk4-7 L2) ----
    const char* AsB = (const char*)&As[c & 1][0];
    floatx4 acc[2][8];
#pragma unroll
    for (int mi = 0; mi < 2; ++mi)
#pragma unroll
      for (int nj = 0; nj < 8; ++nj)
        acc[mi][nj] = (floatx4){0.f, 0.f, 0.f, 0.f};

    __builtin_amdgcn_s_setprio(1);
#pragma unroll
    for (int kk = 0; kk < 8; ++kk) {
      short8 afr[2];
#pragma unroll
      for (int mi = 0; mi < 2; ++mi) {
        const int row = mi * 16 + lcol;
        const int x7 = row & 7;
        const int s0 = (kk * 8 + lrow * 2) ^ x7;
        const int s1 = (kk * 8 + lrow * 2 + 1) ^ x7;
        const floatx4 lo = *reinterpret_cast<const floatx4*>(AsB + (row << 10) + (s0 << 4));
        const floatx4 hi = *reinterpret_cast<const floatx4*>(AsB + (row << 10) + (s1 << 4));
        union { unsigned u[4]; short8 s; } cc;
        cc.u[0] = cvtpk(lo[0], lo[1]);
        cc.u[1] = cvtpk(lo[2], lo[3]);
        cc.u[2] = cvtpk(hi[0], hi[1]);
        cc.u[3] = cvtpk(hi[2], hi[3]);
        afr[mi] = cc.s;
      }
#pragma unroll
      for (int nj = 0; nj < 8; ++nj) {
        const short8 bfr =
            (kk < 4) ? bp[nj][kk]
                     : *reinterpret_cast<const short8*>(Wb + (size_t)nj * 4096 + (kk << 5));
#pragma unroll
        for (int mi = 0; mi < 2; ++mi)
          acc[mi][nj] =
              __builtin_amdgcn_mfma_f32_16x16x32_bf16(afr[mi], bfr, acc[mi][nj], 0, 0, 0);
      }
    }
    __builtin_amdgcn_s_setprio(0);

    // ---- segmented epilogue (uniform run loop over graph boundaries) ----
    const int m0 = c << 5;
    {
      int lo = 0;
      while (true) {
        const int hi = min(ecur - m0, 32);
#pragma unroll
        for (int mi = 0; mi < 2; ++mi)
#pragma unroll
          for (int qq = 0; qq < 4; ++qq) {
            const int r = mi * 16 + lrow * 4 + qq;
            const bool in = (r >= lo) && (r < hi);
#pragma unroll
            for (int nj = 0; nj < 4; ++nj) {
              const float a = acc[mi][nj][qq] + kb[nj];
              const float v = acc[mi][nj + 4][qq] + vb[nj];
              const float e_ = in ? __expf(a) : 0.f;
              den[nj] += e_;
              num[nj] += v * e_;
            }
          }
        if (ecur <= m0 + 32) {
#pragma unroll
          for (int nj = 0; nj < 4; ++nj) {
            float ds = den[nj], ns = num[nj];
            ds += __shfl_xor(ds, 16, 64);
            ds += __shfl_xor(ds, 32, 64);
            ns += __shfl_xor(ns, 16, 64);
            ns += __shfl_xor(ns, 32, 64);
            if (lrow == 0)
              fg[curg & (GPB - 1)][(w << 6) + (nj << 4) + lcol] = ns / (ds + 1e-7f);
            den[nj] = 0.f;
            num[nj] = 0.f;
          }
          ++curg;
          lo = hi;
          ecur = (curg < GPB) ? (eb[curg + 1] - rbase) : 0x7fffffff;
        } else
          break;
        if (curg >= GPB) break;
      }
    }

    // ---- LayerNorm + store for completed graphs (raw barriers: no vmcnt drain) ----
    if (curg > flushed) {
      asm volatile("s_waitcnt lgkmcnt(0)" ::: "memory");
      __builtin_amdgcn_s_barrier();  // fg writes visible
      for (int j = flushed; j < curg; ++j) {
        const float x = fg[j & (GPB - 1)][t];
        float s = x, s2 = x * x;
#pragma unroll
        for (int o = 32; o > 0; o >>= 1) {
          s += __shfl_xor(s, o, 64);
          s2 += __shfl_xor(s2, o, 64);
        }
        if (lane == 0) { redS[w] = s; redS2[w] = s2; }
        asm volatile("s_waitcnt lgkmcnt(0)" ::: "memory");
        __builtin_amdgcn_s_barrier();  // redS visible
        if ((g0 + j) < Gtot) {
          const float ts = redS[0] + redS[1] + redS[2] + redS[3];
          const float ts2 = redS2[0] + redS2[1] + redS2[2] + redS2[3];
          const float mu = ts * (1.f / 256.f);
          const float var = ts2 * (1.f / 256.f) - mu * mu;
          const float inv = rsqrtf(var + 1e-5f);
          out[(size_t)(g0 + j) * 256 + t] = (x - mu) * inv * gamma[t] + beta[t];
        }
        __builtin_amdgcn_s_barrier();  // redS consumed before next j overwrites
      }
      flushed = curg;
    }

    __builtin_amdgcn_s_barrier();  // all waves done reading As[c&1]
    if (c + 2 < nc) stage(c + 2, c & 1);
    if (c + 1 < nc) {
      if (c + 2 < nc)
        asm volatile("s_waitcnt vmcnt(8)" ::: "memory");  // stage(c+1) retired
      else
        asm volatile("s_waitcnt vmcnt(0)" ::: "memory");
      __builtin_amdgcn_s_barrier();  // As[(c+1)&1] published
    }
  }
}

extern "C" void kernel_launch(void* const* d_in, const int* in_sizes, int n_in,
                              void* d_out, int out_size, void* d_ws, size_t ws_size,
                              hipStream_t stream) {
  const float* f_node   = (const float*)d_in[0];
  const float* key_W    = (const float*)d_in[1];
  const float* key_b    = (const float*)d_in[2];
  const float* value_W  = (const float*)d_in[3];
  const float* value_b  = (const float*)d_in[4];
  const float* gamma    = (const float*)d_in[5];
  const float* beta     = (const float*)d_in[6];
  const int*   graph_id = (const int*)d_in[7];
  const int L = in_sizes[0] / 256;
  const int G = out_size / 256;

  char* ws = (char*)d_ws;
  size_t off = 0;
  int* order = (int*)(ws + off); off += (size_t)L * 4;
  off = (off + 255) & ~(size_t)255;
  int* counts = (int*)(ws + off); off += (size_t)G * 4;
  int* offsets = (int*)(ws + off); off += (size_t)(G + 1) * 4;
  int* cursor = (int*)(ws + off); off += (size_t)G * 4;
  off = (off + 255) & ~(size_t)255;
  unsigned short* W2 = (unsigned short*)(ws + off); off += 512 * 256 * 2;

  hipMemsetAsync(counts, 0, (size_t)G * 4, stream);
  k_hist<<<(L + 255) / 256, 256, 0, stream>>>(graph_id, L, counts);
  k_scan<<<1, 1024, 0, stream>>>(counts, offsets, cursor, G);
  k_scatter<<<(L + 255) / 256, 256, 0, stream>>>(graph_id, L, cursor, order);
  k_prepw<<<512, 256, 0, stream>>>(key_W, value_W, W2);
  const int nblk = (G + GPB - 1) / GPB;
  k_fused<<<nblk, 256, 0, stream>>>(f_node, W2, key_b, value_b, gamma, beta, order,
                                    offsets, (float*)d_out, L, G);
}

// Round 12
// 867.327 us; speedup vs baseline: 1.0584x; 1.0584x over previous
//
#include <hip/hip_runtime.h>

typedef short short8 __attribute__((ext_vector_type(8)));
typedef float floatx4 __attribute__((ext_vector_type(4)));

#define GPB 16       // graphs per block -> 256 blocks, exactly 1 resident per CU
#define ORD_CAP 2304 // preloaded order[] entries (span ~1953 +- 44; ~8 sigma headroom)

__device__ __forceinline__ unsigned short f2bf(float x) {
  union { float f; unsigned int u; } c; c.f = x;
  return (unsigned short)((c.u + 0x7FFFu + ((c.u >> 16) & 1u)) >> 16);
}

__device__ __forceinline__ unsigned cvtpk(float lo, float hi) {
  unsigned r;
  asm("v_cvt_pk_bf16_f32 %0, %1, %2" : "=v"(r) : "v"(lo), "v"(hi));
  return r;
}

__device__ __forceinline__ void gld16(const void* g, void* l) {
  __builtin_amdgcn_global_load_lds((const __attribute__((address_space(1))) void*)g,
                                   (__attribute__((address_space(3))) void*)l, 16, 0, 0);
}

__global__ void k_hist(const int* __restrict__ gid, int L, int* __restrict__ counts) {
  int i = blockIdx.x * blockDim.x + threadIdx.x;
  if (i < L) atomicAdd(&counts[gid[i]], 1);
}

__global__ void k_scan(const int* __restrict__ counts, int* __restrict__ offsets,
                       int* __restrict__ cursor, int G) {
  __shared__ int sc[1024];
  int t = threadIdx.x;
  int items = (G + 1023) >> 10;
  int base = t * items;
  int s = 0;
  for (int i = 0; i < items; ++i) { int idx = base + i; if (idx < G) s += counts[idx]; }
  sc[t] = s;
  __syncthreads();
  for (int off = 1; off < 1024; off <<= 1) {
    int v = (t >= off) ? sc[t - off] : 0;
    __syncthreads();
    if (t >= off) sc[t] += v;
    __syncthreads();
  }
  int run = (t == 0) ? 0 : sc[t - 1];
  for (int i = 0; i < items; ++i) {
    int idx = base + i;
    if (idx < G) { offsets[idx] = run; cursor[idx] = run; run += counts[idx]; }
  }
  if (t == 1023) offsets[G] = sc[1023];
}

__global__ void k_scatter(const int* __restrict__ gid, int L, int* __restrict__ cursor,
                          int* __restrict__ order) {
  int i = blockIdx.x * blockDim.x + threadIdx.x;
  if (i < L) {
    int g = gid[i];
    int pos = atomicAdd(&cursor[g], 1);
    order[pos] = i;
  }
}

// W2 [512][256] bf16, 8-wave layout: row j2 -> wv=j2>>6 (wave), half=(j2>>5)&1
// (0 key, 1 val), c=j2&31, d = 32*wv + c.
__global__ void k_prepw(const float* __restrict__ keyW, const float* __restrict__ valW,
                        unsigned short* __restrict__ W2) {
  int j2 = blockIdx.x;
  int k = threadIdx.x;
  int wv = j2 >> 6, half = (j2 >> 5) & 1, c = j2 & 31;
  int d = (wv << 5) + c;
  const float* src = half ? valW : keyW;
  W2[j2 * 256 + k] = f2bf(src[d * 256 + k]);
}

__launch_bounds__(512, 1)
__global__ void k_fused(const float* __restrict__ fnode,
                        const unsigned short* __restrict__ W2,
                        const float* __restrict__ key_b, const float* __restrict__ value_b,
                        const float* __restrict__ gamma, const float* __restrict__ beta,
                        const int* __restrict__ order, const int* __restrict__ offsets,
                        float* __restrict__ out, int L, int Gtot) {
  // A dbuf: 2 x (64 rows x 1KB f32), filled by global_load_lds.
  // LDS 16B-slot s of row r holds global slot s ^ (r&7) (source-side XOR swizzle).
  __shared__ __align__(16) float As[2][64 * 256];
  __shared__ int ord_s[ORD_CAP];
  __shared__ float fg[GPB][256];
  __shared__ int eb[GPB + 1];
  __shared__ float redS[4], redS2[4];

  const int t = threadIdx.x;
  const int lane = t & 63;
  const int w = t >> 6;        // wave 0..7 -> d range [32w, 32w+32)
  const int lcol = lane & 15;
  const int lrow = lane >> 4;
  const int g0 = blockIdx.x * GPB;

  if (t <= GPB) eb[t] = offsets[min(g0 + t, Gtot)];
  __syncthreads();
  const int rbase = eb[0];
  const int span = eb[GPB] - rbase;
  const int nc = max(1, (span + 63) >> 6);

  for (int i = t; i < ORD_CAP; i += 512) ord_s[i] = order[min(rbase + i, L - 1)];

  float kb[2], vb[2];
#pragma unroll
  for (int nj = 0; nj < 2; ++nj) {
    int d = (w << 5) + (nj << 4) + lcol;
    kb[nj] = key_b[d];
    vb[nj] = value_b[d];
  }
  const unsigned short* Wn[4];  // nj 0-1 key, 2-3 val (same d as nj-2)
#pragma unroll
  for (int nj = 0; nj < 4; ++nj)
    Wn[nj] = W2 + ((size_t)((w << 6) + ((nj >> 1) << 5) + ((nj & 1) << 4) + lcol)) * 256 +
             lrow * 8;
  short8 bp[4][4];  // kk 0..3 register-resident; kk 4..7 streamed from L2
#pragma unroll
  for (int nj = 0; nj < 4; ++nj)
#pragma unroll
    for (int kk = 0; kk < 4; ++kk)
      bp[nj][kk] = *reinterpret_cast<const short8*>(Wn[nj] + (kk << 5));

  __syncthreads();  // ord_s ready

  // stage chunk c into buffer buf: wave w gathers rows [8w, 8w+8), 1KB row per gld16x64
  auto stage = [&](int c, int buf) {
    const int m0 = c << 6;
#pragma unroll
    for (int it = 0; it < 8; ++it) {
      int gi = m0 + (w << 3) + it;
      if (gi > span - 1) gi = span - 1;
      const int idx = (gi < ORD_CAP) ? ord_s[gi] : order[rbase + gi];
      const char* gsrc =
          (const char*)fnode + ((size_t)idx << 10) + ((lane << 4) ^ (it << 4));
      gld16(gsrc, (char*)&As[buf][0] + (((w << 3) + it) << 10));
    }
  };

  // ---- MFMA on chunk c into acc (A from LDS f32->bf16 at frag load) ----
  auto mfma_chunk = [&](floatx4 (&acc)[4][4], int c) {
    const char* AsB = (const char*)&As[c & 1][0];
#pragma unroll
    for (int mi = 0; mi < 4; ++mi)
#pragma unroll
      for (int nj = 0; nj < 4; ++nj)
        acc[mi][nj] = (floatx4){0.f, 0.f, 0.f, 0.f};
#pragma unroll
    for (int kk = 0; kk < 8; ++kk) {
      short8 afr[4];
#pragma unroll
      for (int mi = 0; mi < 4; ++mi) {
        const int row = mi * 16 + lcol;
        const int x7 = row & 7;
        const int s0 = (kk * 8 + lrow * 2) ^ x7;
        const int s1 = (kk * 8 + lrow * 2 + 1) ^ x7;
        const floatx4 lo = *reinterpret_cast<const floatx4*>(AsB + (row << 10) + (s0 << 4));
        const floatx4 hi = *reinterpret_cast<const floatx4*>(AsB + (row << 10) + (s1 << 4));
        union { unsigned u[4]; short8 s; } cc;
        cc.u[0] = cvtpk(lo[0], lo[1]);
        cc.u[1] = cvtpk(lo[2], lo[3]);
        cc.u[2] = cvtpk(hi[0], hi[1]);
        cc.u[3] = cvtpk(hi[2], hi[3]);
        afr[mi] = cc.s;
      }
#pragma unroll
      for (int nj = 0; nj < 4; ++nj) {
        const short8 bfr = (kk < 4)
                               ? bp[nj][kk]
                               : *reinterpret_cast<const short8*>(Wn[nj] + (kk << 5));
#pragma unroll
        for (int mi = 0; mi < 4; ++mi)
          acc[mi][nj] =
              __builtin_amdgcn_mfma_f32_16x16x32_bf16(afr[mi], bfr, acc[mi][nj], 0, 0, 0);
      }
    }
  };

  int curg = 0;
  int ecur = eb[1] - rbase;
  float den[2] = {0.f, 0.f};
  float num[2] = {0.f, 0.f};

  // ---- segmented epilogue for chunk c on acc (writes fg, no barriers) ----
  auto epi_chunk = [&](floatx4 (&acc)[4][4], int c) {
    const int m0 = c << 6;
    int lo = 0;
    while (true) {
      const int hi = min(ecur - m0, 64);
      const bool full = (lo == 0) && (hi >= 64);  // uniform fast path: no masking
#pragma unroll
      for (int mi = 0; mi < 4; ++mi)
#pragma unroll
        for (int qq = 0; qq < 4; ++qq) {
          const int r = mi * 16 + lrow * 4 + qq;
          const bool in = full || ((r >= lo) && (r < hi));
#pragma unroll
          for (int nj = 0; nj < 2; ++nj) {
            const float a = acc[mi][nj][qq] + kb[nj];
            const float v = acc[mi][nj + 2][qq] + vb[nj];
            const float e_ = in ? __expf(a) : 0.f;
            den[nj] += e_;
            num[nj] += v * e_;
          }
        }
      if (ecur <= m0 + 64) {
#pragma unroll
        for (int nj = 0; nj < 2; ++nj) {
          float ds = den[nj], ns = num[nj];
          ds += __shfl_xor(ds, 16, 64);
          ds += __shfl_xor(ds, 32, 64);
          ns += __shfl_xor(ns, 16, 64);
          ns += __shfl_xor(ns, 32, 64);
          if (lrow == 0)
            fg[curg & (GPB - 1)][(w << 5) + (nj << 4) + lcol] = ns / (ds + 1e-7f);
          den[nj] = 0.f;
          num[nj] = 0.f;
        }
        ++curg;
        lo = hi;
        ecur = (curg < GPB) ? (eb[curg + 1] - rbase) : 0x7fffffff;
      } else
        break;
      if (curg >= GPB) break;
    }
  };

  floatx4 accA[4][4], accB[4][4];

  stage(0, 0);
  if (nc > 1) {
    stage(1, 1);
    asm volatile("s_waitcnt vmcnt(8)" ::: "memory");  // chunk 0's 8 gld retired (FIFO)
  } else {
    asm volatile("s_waitcnt vmcnt(0)" ::: "memory");
  }
  __builtin_amdgcn_s_barrier();

  // chunk 0 (no lagged epilogue yet)
  mfma_chunk(accA, 0);
  __builtin_amdgcn_s_barrier();  // all waves done reading As[0]
  if (2 < nc) stage(2, 0);

  for (int c = 1; c < nc; ++c) {
    if (c + 1 < nc)
      asm volatile("s_waitcnt vmcnt(8)" ::: "memory");  // stage(c) retired
    else
      asm volatile("s_waitcnt vmcnt(0)" ::: "memory");
    __builtin_amdgcn_s_barrier();  // As[c&1] published

    // MFMA(c) and epilogue(c-1) share one barrier-free region -> dual-issue overlap
    if (c & 1) {
      mfma_chunk(accB, c);
      epi_chunk(accA, c - 1);
    } else {
      mfma_chunk(accA, c);
      epi_chunk(accB, c - 1);
    }

    __builtin_amdgcn_s_barrier();  // all waves done reading As[c&1]
    if (c + 2 < nc) stage(c + 2, c & 1);
  }

  // tail epilogue for last chunk
  if ((nc - 1) & 1)
    epi_chunk(accB, nc - 1);
  else
    epi_chunk(accA, nc - 1);

  __syncthreads();  // all fg writes visible

  // ---- LayerNorm + store for all GPB graphs at block end ----
  for (int j = 0; j < GPB; ++j) {
    float x = 0.f;
    if (t < 256) x = fg[j][t];
    float s = x, s2 = x * x;
#pragma unroll
    for (int o = 32; o > 0; o >>= 1) {
      s += __shfl_xor(s, o, 64);
      s2 += __shfl_xor(s2, o, 64);
    }
    if (t < 256 && lane == 0) { redS[w] = s; redS2[w] = s2; }
    __syncthreads();
    if (t < 256 && (g0 + j) < Gtot) {
      const float ts = redS[0] + redS[1] + redS[2] + redS[3];
      const float ts2 = redS2[0] + redS2[1] + redS2[2] + redS2[3];
      const float mu = ts * (1.f / 256.f);
      const float var = ts2 * (1.f / 256.f) - mu * mu;
      const float inv = rsqrtf(var + 1e-5f);
      out[(size_t)(g0 + j) * 256 + t] = (x - mu) * inv * gamma[t] + beta[t];
    }
    __syncthreads();
  }
}

extern "C" void kernel_launch(void* const* d_in, const int* in_sizes, int n_in,
                              void* d_out, int out_size, void* d_ws, size_t ws_size,
                              hipStream_t stream) {
  const float* f_node   = (const float*)d_in[0];
  const float* key_W    = (const float*)d_in[1];
  const float* key_b    = (const float*)d_in[2];
  const float* value_W  = (const float*)d_in[3];
  const float* value_b  = (const float*)d_in[4];
  const float* gamma    = (const float*)d_in[5];
  const float* beta     = (const float*)d_in[6];
  const int*   graph_id = (const int*)d_in[7];
  const int L = in_sizes[0] / 256;
  const int G = out_size / 256;

  char* ws = (char*)d_ws;
  size_t off = 0;
  int* order = (int*)(ws + off); off += (size_t)L * 4;
  off = (off + 255) & ~(size_t)255;
  int* counts = (int*)(ws + off); off += (size_t)G * 4;
  int* offsets = (int*)(ws + off); off += (size_t)(G + 1) * 4;
  int* cursor = (int*)(ws + off); off += (size_t)G * 4;
  off = (off + 255) & ~(size_t)255;
  unsigned short* W2 = (unsigned short*)(ws + off); off += 512 * 256 * 2;

  hipMemsetAsync(counts, 0, (size_t)G * 4, stream);
  k_hist<<<(L + 255) / 256, 256, 0, stream>>>(graph_id, L, counts);
  k_scan<<<1, 1024, 0, stream>>>(counts, offsets, cursor, G);
  k_scatter<<<(L + 255) / 256, 256, 0, stream>>>(graph_id, L, cursor, order);
  k_prepw<<<512, 256, 0, stream>>>(key_W, value_W, W2);
  const int nblk = (G + GPB - 1) / GPB;
  k_fused<<<nblk, 512, 0, stream>>>(f_node, W2, key_b, value_b, gamma, beta, order,
                                    offsets, (float*)d_out, L, G);
}

// Round 13
// 490.070 us; speedup vs baseline: 1.8731x; 1.7698x over previous
//
#include <hip/hip_runtime.h>

typedef short short8 __attribute__((ext_vector_type(8)));
typedef float floatx4 __attribute__((ext_vector_type(4)));

#define GPB 16       // graphs per block -> 256 blocks, exactly 1 resident per CU
#define ORD_CAP 2304 // preloaded order[] entries (span ~1953 +- 44; ~8 sigma headroom)

__device__ __forceinline__ unsigned short f2bf(float x) {
  union { float f; unsigned int u; } c; c.f = x;
  return (unsigned short)((c.u + 0x7FFFu + ((c.u >> 16) & 1u)) >> 16);
}

__device__ __forceinline__ unsigned cvtpk(float lo, float hi) {
  unsigned r;
  asm("v_cvt_pk_bf16_f32 %0, %1, %2" : "=v"(r) : "v"(lo), "v"(hi));
  return r;
}

__device__ __forceinline__ void gld16(const void* g, void* l) {
  __builtin_amdgcn_global_load_lds((const __attribute__((address_space(1))) void*)g,
                                   (__attribute__((address_space(3))) void*)l, 16, 0, 0);
}

__global__ void k_hist(const int* __restrict__ gid, int L, int* __restrict__ counts) {
  int i = blockIdx.x * blockDim.x + threadIdx.x;
  if (i < L) atomicAdd(&counts[gid[i]], 1);
}

__global__ void k_scan(const int* __restrict__ counts, int* __restrict__ offsets,
                       int* __restrict__ cursor, int G) {
  __shared__ int sc[1024];
  int t = threadIdx.x;
  int items = (G + 1023) >> 10;
  int base = t * items;
  int s = 0;
  for (int i = 0; i < items; ++i) { int idx = base + i; if (idx < G) s += counts[idx]; }
  sc[t] = s;
  __syncthreads();
  for (int off = 1; off < 1024; off <<= 1) {
    int v = (t >= off) ? sc[t - off] : 0;
    __syncthreads();
    if (t >= off) sc[t] += v;
    __syncthreads();
  }
  int run = (t == 0) ? 0 : sc[t - 1];
  for (int i = 0; i < items; ++i) {
    int idx = base + i;
    if (idx < G) { offsets[idx] = run; cursor[idx] = run; run += counts[idx]; }
  }
  if (t == 1023) offsets[G] = sc[1023];
}

__global__ void k_scatter(const int* __restrict__ gid, int L, int* __restrict__ cursor,
                          int* __restrict__ order) {
  int i = blockIdx.x * blockDim.x + threadIdx.x;
  if (i < L) {
    int g = gid[i];
    int pos = atomicAdd(&cursor[g], 1);
    order[pos] = i;
  }
}

// W2 [512][256] bf16, 8-wave layout: row j2 -> wv=j2>>6 (wave), half=(j2>>5)&1
// (0 key, 1 val), c=j2&31, d = 32*wv + c.
__global__ void k_prepw(const float* __restrict__ keyW, const float* __restrict__ valW,
                        unsigned short* __restrict__ W2) {
  int j2 = blockIdx.x;
  int k = threadIdx.x;
  int wv = j2 >> 6, half = (j2 >> 5) & 1, c = j2 & 31;
  int d = (wv << 5) + c;
  const float* src = half ? valW : keyW;
  W2[j2 * 256 + k] = f2bf(src[d * 256 + k]);
}

// stream f_node f32 -> bf16 once (removes 8x duplicated cvt + halves gather bytes)
__global__ void k_cvt(const float* __restrict__ in, unsigned short* __restrict__ out,
                      long n) {
  long i = ((long)blockIdx.x * blockDim.x + threadIdx.x) * 8;
  const long stride = (long)gridDim.x * blockDim.x * 8;
  for (; i + 7 < n; i += stride) {
    const float4 a = *reinterpret_cast<const float4*>(in + i);
    const float4 b = *reinterpret_cast<const float4*>(in + i + 4);
    uint4 o;
    o.x = cvtpk(a.x, a.y);
    o.y = cvtpk(a.z, a.w);
    o.z = cvtpk(b.x, b.y);
    o.w = cvtpk(b.z, b.w);
    *reinterpret_cast<uint4*>(out + i) = o;
  }
}

// BF=1: gather pre-converted bf16 rows (512B), single b128 frag reads, no cvt.
// BF=0: R10 fallback (f32 rows, cvt at frag load) when ws can't hold fnode_bf16.
template <int BF>
__launch_bounds__(512, 1)
__global__ void k_fused(const float* __restrict__ fnode,
                        const unsigned short* __restrict__ fnb,
                        const unsigned short* __restrict__ W2,
                        const float* __restrict__ key_b, const float* __restrict__ value_b,
                        const float* __restrict__ gamma, const float* __restrict__ beta,
                        const int* __restrict__ order, const int* __restrict__ offsets,
                        float* __restrict__ out, int L, int Gtot) {
  // A dbuf. BF=1: 64 rows x 512B bf16, 16B-slot s of row r holds logical slot s^(r&7).
  //         BF=0: 64 rows x 1KB f32, same XOR keyed by (r&7).
  __shared__ __align__(16) char Asb[2][BF ? 32768 : 65536];
  __shared__ int ord_s[ORD_CAP];
  __shared__ float fg[GPB][256];
  __shared__ int eb[GPB + 1];
  __shared__ float redS[4], redS2[4];

  const int t = threadIdx.x;
  const int lane = t & 63;
  const int w = t >> 6;        // wave 0..7 -> d range [32w, 32w+32)
  const int lcol = lane & 15;
  const int lrow = lane >> 4;
  const int g0 = blockIdx.x * GPB;

  if (t <= GPB) eb[t] = offsets[min(g0 + t, Gtot)];
  __syncthreads();
  const int rbase = eb[0];
  const int span = eb[GPB] - rbase;
  const int nc = max(1, (span + 63) >> 6);

  for (int i = t; i < ORD_CAP; i += 512) ord_s[i] = order[min(rbase + i, L - 1)];

  float kb[2], vb[2];
#pragma unroll
  for (int nj = 0; nj < 2; ++nj) {
    int d = (w << 5) + (nj << 4) + lcol;
    kb[nj] = key_b[d];
    vb[nj] = value_b[d];
  }
  const unsigned short* Wn[4];  // nj 0-1 key, 2-3 val (same d as nj-2)
#pragma unroll
  for (int nj = 0; nj < 4; ++nj)
    Wn[nj] = W2 + ((size_t)((w << 6) + ((nj >> 1) << 5) + ((nj & 1) << 4) + lcol)) * 256 +
             lrow * 8;
  short8 bp[4][4];  // kk 0..3 register-resident; kk 4..7 streamed from L2
#pragma unroll
  for (int nj = 0; nj < 4; ++nj)
#pragma unroll
    for (int kk = 0; kk < 4; ++kk)
      bp[nj][kk] = *reinterpret_cast<const short8*>(Wn[nj] + (kk << 5));

  __syncthreads();  // ord_s ready

  // stage chunk c into buffer buf
  auto stage = [&](int c, int buf) {
    const int m0 = c << 6;
    if constexpr (BF) {
      // 4 gld/wave, each covers 2 bf16 rows (lanes 0-31 row 2j, 32-63 row 2j+1)
#pragma unroll
      for (int j = 0; j < 4; ++j) {
        const int r = (w << 3) + (j << 1) + (lane >> 5);
        int gi = m0 + r;
        if (gi > span - 1) gi = span - 1;
        if (gi < 0) gi = 0;
        const int idx = (gi < ORD_CAP) ? ord_s[gi] : order[rbase + gi];
        const char* gsrc = (const char*)fnb + ((size_t)idx << 9) +
                           (((lane & 31) ^ (r & 7)) << 4);
        gld16(gsrc, Asb[buf] + (((w << 3) + (j << 1)) << 9));
      }
    } else {
      // 8 gld/wave, 1KB f32 row each
#pragma unroll
      for (int it = 0; it < 8; ++it) {
        int gi = m0 + (w << 3) + it;
        if (gi > span - 1) gi = span - 1;
        if (gi < 0) gi = 0;
        const int idx = (gi < ORD_CAP) ? ord_s[gi] : order[rbase + gi];
        const char* gsrc =
            (const char*)fnode + ((size_t)idx << 10) + ((lane << 4) ^ (it << 4));
        gld16(gsrc, Asb[buf] + (((w << 3) + it) << 10));
      }
    }
  };
  auto wait_stage = [&](bool counted) {
    if (counted) {
      if constexpr (BF)
        asm volatile("s_waitcnt vmcnt(4)" ::: "memory");
      else
        asm volatile("s_waitcnt vmcnt(8)" ::: "memory");
    } else {
      asm volatile("s_waitcnt vmcnt(0)" ::: "memory");
    }
  };

  // ---- MFMA on chunk c into acc ----
  auto mfma_chunk = [&](floatx4 (&acc)[4][4], int c) {
    const char* AsB = Asb[c & 1];
#pragma unroll
    for (int mi = 0; mi < 4; ++mi)
#pragma unroll
      for (int nj = 0; nj < 4; ++nj)
        acc[mi][nj] = (floatx4){0.f, 0.f, 0.f, 0.f};
#pragma unroll
    for (int kk = 0; kk < 8; ++kk) {
      short8 afr[4];
#pragma unroll
      for (int mi = 0; mi < 4; ++mi) {
        const int row = mi * 16 + lcol;
        const int x7 = row & 7;
        if constexpr (BF) {
          afr[mi] = *reinterpret_cast<const short8*>(
              AsB + (row << 9) + (((kk * 4 + lrow) ^ x7) << 4));
        } else {
          const int s0 = (kk * 8 + lrow * 2) ^ x7;
          const int s1 = (kk * 8 + lrow * 2 + 1) ^ x7;
          const floatx4 lo =
              *reinterpret_cast<const floatx4*>(AsB + (row << 10) + (s0 << 4));
          const floatx4 hi =
              *reinterpret_cast<const floatx4*>(AsB + (row << 10) + (s1 << 4));
          union { unsigned u[4]; short8 s; } cc;
          cc.u[0] = cvtpk(lo[0], lo[1]);
          cc.u[1] = cvtpk(lo[2], lo[3]);
          cc.u[2] = cvtpk(hi[0], hi[1]);
          cc.u[3] = cvtpk(hi[2], hi[3]);
          afr[mi] = cc.s;
        }
      }
#pragma unroll
      for (int nj = 0; nj < 4; ++nj) {
        const short8 bfr = (kk < 4)
                               ? bp[nj][kk]
                               : *reinterpret_cast<const short8*>(Wn[nj] + (kk << 5));
#pragma unroll
        for (int mi = 0; mi < 4; ++mi)
          acc[mi][nj] =
              __builtin_amdgcn_mfma_f32_16x16x32_bf16(afr[mi], bfr, acc[mi][nj], 0, 0, 0);
      }
    }
  };

  int curg = 0;
  int ecur = eb[1] - rbase;
  float den[2] = {0.f, 0.f};
  float num[2] = {0.f, 0.f};

  auto epi_chunk = [&](floatx4 (&acc)[4][4], int c) {
    const int m0 = c << 6;
    int lo = 0;
    while (true) {
      const int hi = min(ecur - m0, 64);
      const bool full = (lo == 0) && (hi >= 64);
#pragma unroll
      for (int mi = 0; mi < 4; ++mi)
#pragma unroll
        for (int qq = 0; qq < 4; ++qq) {
          const int r = mi * 16 + lrow * 4 + qq;
          const bool in = full || ((r >= lo) && (r < hi));
#pragma unroll
          for (int nj = 0; nj < 2; ++nj) {
            const float a = acc[mi][nj][qq] + kb[nj];
            const float v = acc[mi][nj + 2][qq] + vb[nj];
            const float e_ = in ? __expf(a) : 0.f;
            den[nj] += e_;
            num[nj] += v * e_;
          }
        }
      if (ecur <= m0 + 64) {
#pragma unroll
        for (int nj = 0; nj < 2; ++nj) {
          float ds = den[nj], ns = num[nj];
          ds += __shfl_xor(ds, 16, 64);
          ds += __shfl_xor(ds, 32, 64);
          ns += __shfl_xor(ns, 16, 64);
          ns += __shfl_xor(ns, 32, 64);
          if (lrow == 0)
            fg[curg & (GPB - 1)][(w << 5) + (nj << 4) + lcol] = ns / (ds + 1e-7f);
          den[nj] = 0.f;
          num[nj] = 0.f;
        }
        ++curg;
        lo = hi;
        ecur = (curg < GPB) ? (eb[curg + 1] - rbase) : 0x7fffffff;
      } else
        break;
      if (curg >= GPB) break;
    }
  };

  floatx4 acc[4][4];

  stage(0, 0);
  if (nc > 1) {
    stage(1, 1);
    wait_stage(true);
  } else {
    wait_stage(false);
  }
  __builtin_amdgcn_s_barrier();

  for (int c = 0; c < nc; ++c) {
    __builtin_amdgcn_s_setprio(1);
    mfma_chunk(acc, c);
    __builtin_amdgcn_s_setprio(0);
    epi_chunk(acc, c);
    __builtin_amdgcn_s_barrier();  // all waves done reading Asb[c&1]
    if (c + 2 < nc) stage(c + 2, c & 1);
    if (c + 1 < nc) {
      wait_stage(c + 2 < nc);      // stage(c+1) retired
      __builtin_amdgcn_s_barrier();  // Asb[(c+1)&1] published
    }
  }

  __syncthreads();  // all fg writes visible

  // ---- LayerNorm + store for all GPB graphs at block end ----
  for (int j = 0; j < GPB; ++j) {
    float x = 0.f;
    if (t < 256) x = fg[j][t];
    float s = x, s2 = x * x;
#pragma unroll
    for (int o = 32; o > 0; o >>= 1) {
      s += __shfl_xor(s, o, 64);
      s2 += __shfl_xor(s2, o, 64);
    }
    if (t < 256 && lane == 0) { redS[w] = s; redS2[w] = s2; }
    __syncthreads();
    if (t < 256 && (g0 + j) < Gtot) {
      const float ts = redS[0] + redS[1] + redS[2] + redS[3];
      const float ts2 = redS2[0] + redS2[1] + redS2[2] + redS2[3];
      const float mu = ts * (1.f / 256.f);
      const float var = ts2 * (1.f / 256.f) - mu * mu;
      const float inv = rsqrtf(var + 1e-5f);
      out[(size_t)(g0 + j) * 256 + t] = (x - mu) * inv * gamma[t] + beta[t];
    }
    __syncthreads();
  }
}

extern "C" void kernel_launch(void* const* d_in, const int* in_sizes, int n_in,
                              void* d_out, int out_size, void* d_ws, size_t ws_size,
                              hipStream_t stream) {
  const float* f_node   = (const float*)d_in[0];
  const float* key_W    = (const float*)d_in[1];
  const float* key_b    = (const float*)d_in[2];
  const float* value_W  = (const float*)d_in[3];
  const float* value_b  = (const float*)d_in[4];
  const float* gamma    = (const float*)d_in[5];
  const float* beta     = (const float*)d_in[6];
  const int*   graph_id = (const int*)d_in[7];
  const int L = in_sizes[0] / 256;
  const int G = out_size / 256;

  char* ws = (char*)d_ws;
  size_t off = 0;
  int* order = (int*)(ws + off); off += (size_t)L * 4;
  off = (off + 255) & ~(size_t)255;
  int* counts = (int*)(ws + off); off += (size_t)G * 4;
  int* offsets = (int*)(ws + off); off += (size_t)(G + 1) * 4;
  int* cursor = (int*)(ws + off); off += (size_t)G * 4;
  off = (off + 255) & ~(size_t)255;
  unsigned short* W2 = (unsigned short*)(ws + off); off += 512 * 256 * 2;
  off = (off + 255) & ~(size_t)255;
  unsigned short* fnb = (unsigned short*)(ws + off);
  const size_t need = off + (size_t)L * 256 * 2;
  const bool useBF = (ws_size >= need);

  hipMemsetAsync(counts, 0, (size_t)G * 4, stream);
  k_hist<<<(L + 255) / 256, 256, 0, stream>>>(graph_id, L, counts);
  k_scan<<<1, 1024, 0, stream>>>(counts, offsets, cursor, G);
  k_scatter<<<(L + 255) / 256, 256, 0, stream>>>(graph_id, L, cursor, order);
  k_prepw<<<512, 256, 0, stream>>>(key_W, value_W, W2);
  if (useBF)
    k_cvt<<<2048, 256, 0, stream>>>(f_node, fnb, (long)L * 256);
  const int nblk = (G + GPB - 1) / GPB;
  if (useBF)
    k_fused<1><<<nblk, 512, 0, stream>>>(f_node, fnb, W2, key_b, value_b, gamma, beta,
                                         order, offsets, (float*)d_out, L, G);
  else
    k_fused<0><<<nblk, 512, 0, stream>>>(f_node, fnb, W2, key_b, value_b, gamma, beta,
                                         order, offsets, (float*)d_out, L, G);
}